// Round 18
// baseline (199.991 us; speedup 1.0000x reference)
//
#include <hip/hip_runtime.h>

#define SEQ   4096
#define CDIM  256
#define NHEAD 4
#define DHEAD 64
#define PSTRIDE 72   // P-buffer row stride (f16): 144 B rows -> 16B-aligned b128 reads
#define LOG2E 1.4426950408889634f

typedef float    f32x4 __attribute__((ext_vector_type(4)));
typedef _Float16 f16x8 __attribute__((ext_vector_type(8)));
typedef _Float16 f16x4 __attribute__((ext_vector_type(4)));
typedef _Float16 f16x2 __attribute__((ext_vector_type(2)));

__device__ __forceinline__ f16x8 cvt_frag(const float* __restrict__ p) {
    float4 f0 = *(const float4*)p;
    float4 f1 = *(const float4*)(p + 4);
    f16x8 r;
    r[0]=(_Float16)f0.x; r[1]=(_Float16)f0.y; r[2]=(_Float16)f0.z; r[3]=(_Float16)f0.w;
    r[4]=(_Float16)f1.x; r[5]=(_Float16)f1.y; r[6]=(_Float16)f1.z; r[7]=(_Float16)f1.w;
    return r;
}

// cvt_pkrtz returns __fp16x2; bit-cast to our _Float16x2 (identical layout).
__device__ __forceinline__ f16x2 pkrtz(float a, float b) {
    return __builtin_bit_cast(f16x2, __builtin_amdgcn_cvt_pkrtz(a, b));
}

// ---------------- Kernel 0: weight fp32->fp16 prep ----------------
// KEEP (r13 lesson: converting in consumers re-converts per block, +50us VALU).
__global__ __launch_bounds__(256) void sta_prep(
    const float* __restrict__ qw, const float* __restrict__ kw,
    const float* __restrict__ vw, const float* __restrict__ ow,
    _Float16* __restrict__ w16)
{
    const int mat = blockIdx.y;
    const float* src = (mat == 0) ? qw : (mat == 1) ? kw : (mat == 2) ? vw : ow;
    const int i = (blockIdx.x * 256 + threadIdx.x) * 8;
    *(f16x8*)(w16 + mat * 65536 + i) = cvt_frag(src + i);
}

// ---------------- Kernel 1: QKV projection ----------------
// Q pre-scale folds softmax's base-2 conversion: sc = C^-0.5 * log2(e), so the
// attn kernel's logits are already a*log2e and exp() is a bare v_exp_f32 (2^x).
__global__ __launch_bounds__(256) void sta_qkv(
    const float* __restrict__ x, const _Float16* __restrict__ w16,
    const float* __restrict__ qb, const float* __restrict__ kb, const float* __restrict__ vb,
    _Float16* __restrict__ Qo, _Float16* __restrict__ Ko, _Float16* __restrict__ Vo)
{
    const int wave = threadIdx.x >> 6;
    const int lane = threadIdx.x & 63;
    const int l15  = lane & 15;
    const int quad = lane >> 4;
    const int mat  = blockIdx.y;
    const int half = blockIdx.z;
    const int row0 = blockIdx.x * 64 + wave * 16;

    const _Float16* w    = w16 + mat * 65536;
    const float*    bias = (mat == 0) ? qb : (mat == 1) ? kb : vb;

    f16x8 xf[8];
    const float* xrow = x + (row0 + l15) * CDIM + quad * 8;
    #pragma unroll
    for (int ks = 0; ks < 8; ks++) xf[ks] = cvt_frag(xrow + ks * 32);

    #pragma unroll 1
    for (int ct = 0; ct < 8; ct++) {
        const int ctg = half * 8 + ct;
        const _Float16* wr = w + (ctg * 16 + l15) * CDIM + quad * 8;
        f32x4 acc = {0.f, 0.f, 0.f, 0.f};
        if (mat < 2) {
            #pragma unroll
            for (int ks = 0; ks < 8; ks++)
                acc = __builtin_amdgcn_mfma_f32_16x16x32_f16(*(const f16x8*)(wr + ks * 32), xf[ks], acc, 0, 0, 0);
            const float4 bv = *(const float4*)(bias + ctg * 16 + quad * 4);
            const int c0 = ctg * 16 + quad * 4;
            const int h = c0 >> 6, d0 = c0 & 63;
            const int grow = row0 + l15, b = grow >> 12, n = grow & (SEQ - 1);
            const float sc = (mat == 0) ? (0.0625f * LOG2E) : 1.0f;
            f16x4 o;
            o[0] = (_Float16)((acc[0] + bv.x) * sc);
            o[1] = (_Float16)((acc[1] + bv.y) * sc);
            o[2] = (_Float16)((acc[2] + bv.z) * sc);
            o[3] = (_Float16)((acc[3] + bv.w) * sc);
            _Float16* dst = ((mat == 0) ? Qo : Ko) + (((b * NHEAD + h) * SEQ + n) * DHEAD + d0);
            *(f16x4*)dst = o;
        } else {
            #pragma unroll
            for (int ks = 0; ks < 8; ks++)
                acc = __builtin_amdgcn_mfma_f32_16x16x32_f16(xf[ks], *(const f16x8*)(wr + ks * 32), acc, 0, 0, 0);
            const int c = ctg * 16 + l15;
            const int h = c >> 6, d = c & 63;
            const float bv = bias[c];
            const int grow0 = row0 + quad * 4, b = grow0 >> 12, n0 = grow0 & (SEQ - 1);
            f16x4 o;
            #pragma unroll
            for (int r = 0; r < 4; r++) o[r] = (_Float16)(acc[r] + bv);
            *(f16x4*)(Vo + (((b * NHEAD + h) * DHEAD + d) * SEQ + n0)) = o;
        }
    }
}

// ---------------- Kernel 2: flash attention, 2-stage software pipeline ------------
// r18 = r17 body + __launch_bounds__(64, 2): pin total regs at 256 (128 arch +
// 128 AGPR) = the 2-waves/SIMD boundary. r17 sits at 148 arch -> 1/SIMD; the
// 20-reg squeeze (-14%) should rematerialize, not spill (unlike r7's 170->84).
// SPILL SENTINEL: WRITE_SIZE must stay 33.3 MB; if it balloons, revert to r17.
// STRUCTURAL MAP (17 rounds of evidence):
//  - REGISTER MODEL: waves/SIMD = floor(256/max(archVGPR,AGPR)).
//  - r12: PV one tile late in ONE merged body -> 77us (the big win).
//  - r17: + ones-MFMA denominator (r16-verified numerics) -> 73.9us.
//  - Occupancy not binding for SLIM waves (r15) but r12's 2/SIMD with the FAT
//    pipelined body was the best-performing residency.
//  - Regressions to avoid: r7/r9/r10/r11/r13/r16 (caps-spill, prefetch arrays,
//    restrict-aliased LDS, dual live tiles, in-consumer cvt, wave-split).
__global__ __launch_bounds__(64, 2) void sta_attn(
    const _Float16* __restrict__ Q, const _Float16* __restrict__ K, const _Float16* __restrict__ Vt,
    const float* __restrict__ taup,
    float* __restrict__ Opart, float* __restrict__ lpart)
{
    __shared__ __align__(16) _Float16 pbuf[2 * 64 * PSTRIDE];   // double-buffered, wave-private

    const int lane = threadIdx.x;
    const int l15  = lane & 15;
    const int quad = lane >> 4;
    const int qt = blockIdx.x;   // 0..63
    const int bh = blockIdx.y;   // 0..7
    const int sp = blockIdx.z;   // 0..3
    const float tau2 = __builtin_bit_cast(float, __builtin_amdgcn_readfirstlane(
        __builtin_bit_cast(int, fmaxf(taup[0], 0.0f) * LOG2E)));

    const _Float16* Qb = Q  + bh * SEQ * DHEAD;
    const _Float16* Kb = K  + bh * SEQ * DHEAD;
    const _Float16* Vb = Vt + bh * DHEAD * SEQ;

    const int q0 = qt * 64;

    // LDS P-buffer bases. NO __restrict__: write and read bases alias pbuf.
    _Float16* pw_base = pbuf + l15 * PSTRIDE + quad * 4;        // writes (b64)
    const _Float16* pr_base = pbuf + l15 * PSTRIDE + quad * 8;  // reads  (b128)
    const _Float16* Krow = Kb + l15 * DHEAD + quad * 8;
    const _Float16* Vrow = Vb + l15 * SEQ + quad * 8;

    // Q B-fragments, held for the whole sweep: col=l15 -> q, k=quad*8+j -> d
    f16x8 qf[4][2];
    #pragma unroll
    for (int qb = 0; qb < 4; qb++)
        #pragma unroll
        for (int ks = 0; ks < 2; ks++)
            qf[qb][ks] = *(const f16x8*)(Qb + (q0 + qb * 16 + l15) * DHEAD + ks * 32 + quad * 8);

    f32x4 O[4][4];     // [qb][db] PV accumulators
    f32x4 accd[4];     // [qb] denominator accumulators (ones-MFMA, r16-verified)
    #pragma unroll
    for (int qb = 0; qb < 4; qb++) {
        accd[qb] = (f32x4){0.f, 0.f, 0.f, 0.f};
        #pragma unroll
        for (int db = 0; db < 4; db++) O[qb][db] = (f32x4){0.f, 0.f, 0.f, 0.f};
    }
    f16x8 ones;
    #pragma unroll
    for (int j = 0; j < 8; j++) ones[j] = (_Float16)1.0f;

    const int kt0 = sp * 16;

    // ---- prologue: QK^T + gate for tile 0 into buffer 0 (no PV yet) ----
    {
        const _Float16* Kt = Krow + (kt0 * 64) * DHEAD;
        #pragma unroll
        for (int kb = 0; kb < 4; kb++) {
            f16x8 k0 = *(const f16x8*)(Kt + kb * 16 * DHEAD);
            f16x8 k1 = *(const f16x8*)(Kt + kb * 16 * DHEAD + 32);
            #pragma unroll
            for (int qb = 0; qb < 4; qb++) {
                f32x4 a = {0.f, 0.f, 0.f, 0.f};
                a = __builtin_amdgcn_mfma_f32_16x16x32_f16(k0, qf[qb][0], a, 0, 0, 0);
                a = __builtin_amdgcn_mfma_f32_16x16x32_f16(k1, qf[qb][1], a, 0, 0, 0);
                float p0 = (a[0] > tau2) ? __builtin_amdgcn_exp2f(a[0]) : 1.0f;
                float p1 = (a[1] > tau2) ? __builtin_amdgcn_exp2f(a[1]) : 1.0f;
                float p2 = (a[2] > tau2) ? __builtin_amdgcn_exp2f(a[2]) : 1.0f;
                float p3 = (a[3] > tau2) ? __builtin_amdgcn_exp2f(a[3]) : 1.0f;
                f16x2 lo = pkrtz(p0, p1);
                f16x2 hi = pkrtz(p2, p3);
                f16x4 pk;
                pk[0] = lo[0]; pk[1] = lo[1]; pk[2] = hi[0]; pk[3] = hi[1];
                *(f16x4*)(pw_base + qb * 16 * PSTRIDE + kb * 16) = pk;
            }
        }
    }

    // ---- steady state: merged { QK(t) -> buf[t&1] } / { PV+denom(t-1) } ----
    #pragma unroll 1
    for (int t = 1; t < 16; t++) {
        const int kvc = (kt0 + t) * 64;        // current tile (QK^T)
        const int kvp = kvc - 64;              // previous tile (PV)
        _Float16* pw = pw_base + (t & 1) * (64 * PSTRIDE);
        const _Float16* pr = pr_base + ((t & 1) ^ 1) * (64 * PSTRIDE);
        const _Float16* Kt = Krow + kvc * DHEAD;
        f16x8 pa[4];
        #pragma unroll
        for (int c = 0; c < 4; c++) {
            // -- QK chunk kb=c for tile t
            f16x8 k0 = *(const f16x8*)(Kt + c * 16 * DHEAD);
            f16x8 k1 = *(const f16x8*)(Kt + c * 16 * DHEAD + 32);
            #pragma unroll
            for (int qb = 0; qb < 4; qb++) {
                f32x4 a = {0.f, 0.f, 0.f, 0.f};
                a = __builtin_amdgcn_mfma_f32_16x16x32_f16(k0, qf[qb][0], a, 0, 0, 0);
                a = __builtin_amdgcn_mfma_f32_16x16x32_f16(k1, qf[qb][1], a, 0, 0, 0);
                float p0 = (a[0] > tau2) ? __builtin_amdgcn_exp2f(a[0]) : 1.0f;
                float p1 = (a[1] > tau2) ? __builtin_amdgcn_exp2f(a[1]) : 1.0f;
                float p2 = (a[2] > tau2) ? __builtin_amdgcn_exp2f(a[2]) : 1.0f;
                float p3 = (a[3] > tau2) ? __builtin_amdgcn_exp2f(a[3]) : 1.0f;
                f16x2 lo = pkrtz(p0, p1);
                f16x2 hi = pkrtz(p2, p3);
                f16x4 pk;
                pk[0] = lo[0]; pk[1] = lo[1]; pk[2] = hi[0]; pk[3] = hi[1];
                *(f16x4*)(pw + qb * 16 * PSTRIDE + c * 16) = pk;
            }
            // -- PV quarter for tile t-1: ks = c>>1, db pair = (c&1)*2
            const int ks = c >> 1, db0 = (c & 1) * 2;
            if ((c & 1) == 0) {
                #pragma unroll
                for (int qb = 0; qb < 4; qb++)
                    pa[qb] = *(const f16x8*)(pr + qb * 16 * PSTRIDE + ks * 32);
                // denominator on the idle MFMA pipe, same pa as PV (r16-verified)
                #pragma unroll
                for (int qb = 0; qb < 4; qb++)
                    accd[qb] = __builtin_amdgcn_mfma_f32_16x16x32_f16(pa[qb], ones, accd[qb], 0, 0, 0);
            }
            #pragma unroll
            for (int dd = 0; dd < 2; dd++) {
                const int db = db0 + dd;
                f16x8 vf = *(const f16x8*)(Vrow + db * 16 * SEQ + kvp + ks * 32);
                #pragma unroll
                for (int qb = 0; qb < 4; qb++)
                    O[qb][db] = __builtin_amdgcn_mfma_f32_16x16x32_f16(pa[qb], vf, O[qb][db], 0, 0, 0);
            }
        }
    }

    // ---- pipeline drain: PV + denom for tile 15 from buf[1] ----
    {
        const int kvp = (kt0 + 15) * 64;
        const _Float16* pr = pr_base + (15 & 1) * (64 * PSTRIDE);
        #pragma unroll
        for (int ks = 0; ks < 2; ks++) {
            f16x8 pa[4];
            #pragma unroll
            for (int qb = 0; qb < 4; qb++)
                pa[qb] = *(const f16x8*)(pr + qb * 16 * PSTRIDE + ks * 32);
            #pragma unroll
            for (int qb = 0; qb < 4; qb++)
                accd[qb] = __builtin_amdgcn_mfma_f32_16x16x32_f16(pa[qb], ones, accd[qb], 0, 0, 0);
            #pragma unroll
            for (int db = 0; db < 4; db++) {
                f16x8 vf = *(const f16x8*)(Vrow + db * 16 * SEQ + kvp + ks * 32);
                #pragma unroll
                for (int qb = 0; qb < 4; qb++)
                    O[qb][db] = __builtin_amdgcn_mfma_f32_16x16x32_f16(pa[qb], vf, O[qb][db], 0, 0, 0);
            }
        }
    }

    // ---- epilogue: store fp32 partials (no shuffle reduce - denom is in accd) ----
    float* Ob = Opart + (size_t)((sp * 8 + bh) * SEQ + q0) * DHEAD;
    #pragma unroll
    for (int qb = 0; qb < 4; qb++)
        #pragma unroll
        for (int db = 0; db < 4; db++)
            #pragma unroll
            for (int r = 0; r < 4; r++)
                Ob[(qb * 16 + quad * 4 + r) * DHEAD + db * 16 + l15] = O[qb][db][r];
    // accd[qb][r] = denom for q = q0+qb*16+quad*4+r, replicated over l15
    if (l15 == 0) {
        #pragma unroll
        for (int qb = 0; qb < 4; qb++)
            #pragma unroll
            for (int r = 0; r < 4; r++)
                lpart[(sp * 8 + bh) * SEQ + q0 + qb * 16 + quad * 4 + r] = accd[qb][r];
    }
}

// ---------------- Kernel 3: fused combine + output projection, single pass --------
// Single pass over all 256 output cols (ct 0..15); Opart read once (32 MB);
// f16 pre-converted weights. grid 256 row-blocks x 128 thr.
__global__ __launch_bounds__(128) void sta_oproj2(
    const float* __restrict__ Opart, const float* __restrict__ lpart,
    const _Float16* __restrict__ w16o, const float* __restrict__ ob,
    float* __restrict__ out)
{
    const int wave = threadIdx.x >> 6;
    const int lane = threadIdx.x & 63;
    const int l15  = lane & 15;
    const int quad = lane >> 4;
    const int row0 = blockIdx.x * 32 + wave * 16;

    const int nglob = row0 + l15;
    const int b = nglob >> 12, n = nglob & (SEQ - 1);

    // af[ks][j] = AO[nglob][ks*32 + quad*8 + j]  (h = ks>>1, dh = (ks&1)*32+quad*8+j)
    f16x8 af[8];
    #pragma unroll
    for (int h = 0; h < 4; h++) {
        const int bhh = b * NHEAD + h;
        float lsum = 0.f;
        #pragma unroll
        for (int s = 0; s < 4; s++) lsum += lpart[(s * 8 + bhh) * SEQ + n];
        const float inv = 1.0f / lsum;
        #pragma unroll
        for (int dp = 0; dp < 2; dp++) {
            const int dh0 = dp * 32 + quad * 8;
            float a0x=0.f,a0y=0.f,a0z=0.f,a0w=0.f,a1x=0.f,a1y=0.f,a1z=0.f,a1w=0.f;
            #pragma unroll
            for (int s = 0; s < 4; s++) {
                const float* p = Opart + (size_t)((s * 8 + bhh) * SEQ + n) * DHEAD + dh0;
                const float4 t0 = *(const float4*)p;
                const float4 t1 = *(const float4*)(p + 4);
                a0x += t0.x; a0y += t0.y; a0z += t0.z; a0w += t0.w;
                a1x += t1.x; a1y += t1.y; a1z += t1.z; a1w += t1.w;
            }
            f16x8 v;
            v[0] = (_Float16)(a0x * inv); v[1] = (_Float16)(a0y * inv);
            v[2] = (_Float16)(a0z * inv); v[3] = (_Float16)(a0w * inv);
            v[4] = (_Float16)(a1x * inv); v[5] = (_Float16)(a1y * inv);
            v[6] = (_Float16)(a1z * inv); v[7] = (_Float16)(a1w * inv);
            af[h * 2 + dp] = v;
        }
    }

    #pragma unroll 1
    for (int ct = 0; ct < 16; ct++) {
        const _Float16* wr = w16o + (ct * 16 + l15) * CDIM + quad * 8;
        f32x4 acc = {0.f, 0.f, 0.f, 0.f};
        #pragma unroll
        for (int ks = 0; ks < 8; ks++)
            acc = __builtin_amdgcn_mfma_f32_16x16x32_f16(*(const f16x8*)(wr + ks * 32), af[ks], acc, 0, 0, 0);
        const int c0 = ct * 16 + quad * 4;
        const float4 bv = *(const float4*)(ob + c0);
        float4 res;
        res.x = acc[0] + bv.x; res.y = acc[1] + bv.y;
        res.z = acc[2] + bv.z; res.w = acc[3] + bv.w;
        *(float4*)(out + (size_t)nglob * CDIM + c0) = res;
    }
}

extern "C" void kernel_launch(void* const* d_in, const int* in_sizes, int n_in,
                              void* d_out, int out_size, void* d_ws, size_t ws_size,
                              hipStream_t stream) {
    const float* x   = (const float*)d_in[0];
    const float* qw  = (const float*)d_in[1];
    const float* qb  = (const float*)d_in[2];
    const float* kw  = (const float*)d_in[3];
    const float* kb  = (const float*)d_in[4];
    const float* vw  = (const float*)d_in[5];
    const float* vb  = (const float*)d_in[6];
    const float* ow  = (const float*)d_in[7];
    const float* ob  = (const float*)d_in[8];
    const float* tau = (const float*)d_in[9];

    _Float16* w16 = (_Float16*)d_ws;
    _Float16* Q   = w16 + 262144;
    _Float16* K   = Q + 2097152;
    _Float16* Vt  = K + 2097152;
    float* Opart  = (float*)(Vt + 2097152);           // 4 sp x 8 bh x 4096 x 64 f32 = 32 MB
    float* lpart  = Opart + 8388608;                  // 4 sp x 8 bh x 4096 f32

    sta_prep  <<<dim3(32, 4),      256, 0, stream>>>(qw, kw, vw, ow, w16);
    sta_qkv   <<<dim3(128, 3, 2),  256, 0, stream>>>(x, w16, qb, kb, vb, Q, K, Vt);
    sta_attn  <<<dim3(64, 8, 4),    64, 0, stream>>>(Q, K, Vt, tau, Opart, lpart);
    sta_oproj2<<<256,              128, 0, stream>>>(Opart, lpart, w16 + 3 * 65536, ob, (float*)d_out);
}

// Round 19
// 195.165 us; speedup vs baseline: 1.0247x; 1.0247x over previous
//
#include <hip/hip_runtime.h>

#define SEQ   4096
#define CDIM  256
#define NHEAD 4
#define DHEAD 64
#define PSTRIDE 72   // P-buffer row stride (f16): 144 B rows -> 16B-aligned b128 reads
#define LOG2E 1.4426950408889634f

typedef float    f32x4 __attribute__((ext_vector_type(4)));
typedef _Float16 f16x8 __attribute__((ext_vector_type(8)));
typedef _Float16 f16x4 __attribute__((ext_vector_type(4)));
typedef _Float16 f16x2 __attribute__((ext_vector_type(2)));

__device__ __forceinline__ f16x8 cvt_frag(const float* __restrict__ p) {
    float4 f0 = *(const float4*)p;
    float4 f1 = *(const float4*)(p + 4);
    f16x8 r;
    r[0]=(_Float16)f0.x; r[1]=(_Float16)f0.y; r[2]=(_Float16)f0.z; r[3]=(_Float16)f0.w;
    r[4]=(_Float16)f1.x; r[5]=(_Float16)f1.y; r[6]=(_Float16)f1.z; r[7]=(_Float16)f1.w;
    return r;
}

// cvt_pkrtz returns __fp16x2; bit-cast to our _Float16x2 (identical layout).
__device__ __forceinline__ f16x2 pkrtz(float a, float b) {
    return __builtin_bit_cast(f16x2, __builtin_amdgcn_cvt_pkrtz(a, b));
}

// ---------------- Kernel 0: weight fp32->fp16 prep ----------------
// KEEP (r13 lesson: converting in consumers re-converts per block, +50us VALU).
__global__ __launch_bounds__(256) void sta_prep(
    const float* __restrict__ qw, const float* __restrict__ kw,
    const float* __restrict__ vw, const float* __restrict__ ow,
    _Float16* __restrict__ w16)
{
    const int mat = blockIdx.y;
    const float* src = (mat == 0) ? qw : (mat == 1) ? kw : (mat == 2) ? vw : ow;
    const int i = (blockIdx.x * 256 + threadIdx.x) * 8;
    *(f16x8*)(w16 + mat * 65536 + i) = cvt_frag(src + i);
}

// ---------------- Kernel 1: QKV projection ----------------
// Q pre-scale folds softmax's base-2 conversion: sc = C^-0.5 * log2(e), so the
// attn kernel's logits are already a*log2e and exp() is a bare v_exp_f32 (2^x).
__global__ __launch_bounds__(256) void sta_qkv(
    const float* __restrict__ x, const _Float16* __restrict__ w16,
    const float* __restrict__ qb, const float* __restrict__ kb, const float* __restrict__ vb,
    _Float16* __restrict__ Qo, _Float16* __restrict__ Ko, _Float16* __restrict__ Vo)
{
    const int wave = threadIdx.x >> 6;
    const int lane = threadIdx.x & 63;
    const int l15  = lane & 15;
    const int quad = lane >> 4;
    const int mat  = blockIdx.y;
    const int half = blockIdx.z;
    const int row0 = blockIdx.x * 64 + wave * 16;

    const _Float16* w    = w16 + mat * 65536;
    const float*    bias = (mat == 0) ? qb : (mat == 1) ? kb : vb;

    f16x8 xf[8];
    const float* xrow = x + (row0 + l15) * CDIM + quad * 8;
    #pragma unroll
    for (int ks = 0; ks < 8; ks++) xf[ks] = cvt_frag(xrow + ks * 32);

    #pragma unroll 1
    for (int ct = 0; ct < 8; ct++) {
        const int ctg = half * 8 + ct;
        const _Float16* wr = w + (ctg * 16 + l15) * CDIM + quad * 8;
        f32x4 acc = {0.f, 0.f, 0.f, 0.f};
        if (mat < 2) {
            #pragma unroll
            for (int ks = 0; ks < 8; ks++)
                acc = __builtin_amdgcn_mfma_f32_16x16x32_f16(*(const f16x8*)(wr + ks * 32), xf[ks], acc, 0, 0, 0);
            const float4 bv = *(const float4*)(bias + ctg * 16 + quad * 4);
            const int c0 = ctg * 16 + quad * 4;
            const int h = c0 >> 6, d0 = c0 & 63;
            const int grow = row0 + l15, b = grow >> 12, n = grow & (SEQ - 1);
            const float sc = (mat == 0) ? (0.0625f * LOG2E) : 1.0f;
            f16x4 o;
            o[0] = (_Float16)((acc[0] + bv.x) * sc);
            o[1] = (_Float16)((acc[1] + bv.y) * sc);
            o[2] = (_Float16)((acc[2] + bv.z) * sc);
            o[3] = (_Float16)((acc[3] + bv.w) * sc);
            _Float16* dst = ((mat == 0) ? Qo : Ko) + (((b * NHEAD + h) * SEQ + n) * DHEAD + d0);
            *(f16x4*)dst = o;
        } else {
            #pragma unroll
            for (int ks = 0; ks < 8; ks++)
                acc = __builtin_amdgcn_mfma_f32_16x16x32_f16(xf[ks], *(const f16x8*)(wr + ks * 32), acc, 0, 0, 0);
            const int c = ctg * 16 + l15;
            const int h = c >> 6, d = c & 63;
            const float bv = bias[c];
            const int grow0 = row0 + quad * 4, b = grow0 >> 12, n0 = grow0 & (SEQ - 1);
            f16x4 o;
            #pragma unroll
            for (int r = 0; r < 4; r++) o[r] = (_Float16)(acc[r] + bv);
            *(f16x4*)(Vo + (((b * NHEAD + h) * DHEAD + d) * SEQ + n0)) = o;
        }
    }
}

// ---------------- Kernel 2: flash attention, 2-stage software pipeline ------------
// CONFIG OF RECORD (r17, 73.9us attn / 195.39us total): r12 merged-body
// pipeline (PV one tile late) + ones-MFMA denominator.
// FINAL STRUCTURAL MAP (18 rounds):
//  - REGISTER MODEL: waves/SIMD = floor(256/max(archVGPR,AGPR)). r17 = 148
//    arch -> 1/SIMD, and that is FASTER than the 2/SIMD squeeze (r18: cap at
//    128 arch -> -56 regs of scheduling freedom -> 78.4us). Per-wave schedule
//    richness > residency for this load-latency-bound kernel (also r15: 4
//    slim waves = 128.7us).
//  - r12 win: PV shifted one tile late in ONE merged loop body (cross-
//    iteration restructuring the compiler can't do). P ds_read trails its
//    ds_write by a full tile; exp bursts sit next to independent PV MFMAs.
//  - r17 win: denominator via mfma(P, ones) on the idle matrix pipe, same pa
//    fragments as PV; numerator/denominator share f16 P so biases cancel.
//  - Dead ends (do not revisit): launch_bounds caps (r7/r18), prefetch arrays
//    (r9), __restrict__ on aliasing LDS ptrs (r10 NaN), dual live tiles (r11),
//    in-consumer weight cvt (r13), slim waves (r3/r15), producer-consumer
//    wave split (r16).
__global__ __launch_bounds__(64) void sta_attn(
    const _Float16* __restrict__ Q, const _Float16* __restrict__ K, const _Float16* __restrict__ Vt,
    const float* __restrict__ taup,
    float* __restrict__ Opart, float* __restrict__ lpart)
{
    __shared__ __align__(16) _Float16 pbuf[2 * 64 * PSTRIDE];   // double-buffered, wave-private

    const int lane = threadIdx.x;
    const int l15  = lane & 15;
    const int quad = lane >> 4;
    const int qt = blockIdx.x;   // 0..63
    const int bh = blockIdx.y;   // 0..7
    const int sp = blockIdx.z;   // 0..3
    const float tau2 = __builtin_bit_cast(float, __builtin_amdgcn_readfirstlane(
        __builtin_bit_cast(int, fmaxf(taup[0], 0.0f) * LOG2E)));

    const _Float16* Qb = Q  + bh * SEQ * DHEAD;
    const _Float16* Kb = K  + bh * SEQ * DHEAD;
    const _Float16* Vb = Vt + bh * DHEAD * SEQ;

    const int q0 = qt * 64;

    // LDS P-buffer bases. NO __restrict__: write and read bases alias pbuf.
    _Float16* pw_base = pbuf + l15 * PSTRIDE + quad * 4;        // writes (b64)
    const _Float16* pr_base = pbuf + l15 * PSTRIDE + quad * 8;  // reads  (b128)
    const _Float16* Krow = Kb + l15 * DHEAD + quad * 8;
    const _Float16* Vrow = Vb + l15 * SEQ + quad * 8;

    // Q B-fragments, held for the whole sweep: col=l15 -> q, k=quad*8+j -> d
    f16x8 qf[4][2];
    #pragma unroll
    for (int qb = 0; qb < 4; qb++)
        #pragma unroll
        for (int ks = 0; ks < 2; ks++)
            qf[qb][ks] = *(const f16x8*)(Qb + (q0 + qb * 16 + l15) * DHEAD + ks * 32 + quad * 8);

    f32x4 O[4][4];     // [qb][db] PV accumulators
    f32x4 accd[4];     // [qb] denominator accumulators (ones-MFMA, r16-verified)
    #pragma unroll
    for (int qb = 0; qb < 4; qb++) {
        accd[qb] = (f32x4){0.f, 0.f, 0.f, 0.f};
        #pragma unroll
        for (int db = 0; db < 4; db++) O[qb][db] = (f32x4){0.f, 0.f, 0.f, 0.f};
    }
    f16x8 ones;
    #pragma unroll
    for (int j = 0; j < 8; j++) ones[j] = (_Float16)1.0f;

    const int kt0 = sp * 16;

    // ---- prologue: QK^T + gate for tile 0 into buffer 0 (no PV yet) ----
    {
        const _Float16* Kt = Krow + (kt0 * 64) * DHEAD;
        #pragma unroll
        for (int kb = 0; kb < 4; kb++) {
            f16x8 k0 = *(const f16x8*)(Kt + kb * 16 * DHEAD);
            f16x8 k1 = *(const f16x8*)(Kt + kb * 16 * DHEAD + 32);
            #pragma unroll
            for (int qb = 0; qb < 4; qb++) {
                f32x4 a = {0.f, 0.f, 0.f, 0.f};
                a = __builtin_amdgcn_mfma_f32_16x16x32_f16(k0, qf[qb][0], a, 0, 0, 0);
                a = __builtin_amdgcn_mfma_f32_16x16x32_f16(k1, qf[qb][1], a, 0, 0, 0);
                float p0 = (a[0] > tau2) ? __builtin_amdgcn_exp2f(a[0]) : 1.0f;
                float p1 = (a[1] > tau2) ? __builtin_amdgcn_exp2f(a[1]) : 1.0f;
                float p2 = (a[2] > tau2) ? __builtin_amdgcn_exp2f(a[2]) : 1.0f;
                float p3 = (a[3] > tau2) ? __builtin_amdgcn_exp2f(a[3]) : 1.0f;
                f16x2 lo = pkrtz(p0, p1);
                f16x2 hi = pkrtz(p2, p3);
                f16x4 pk;
                pk[0] = lo[0]; pk[1] = lo[1]; pk[2] = hi[0]; pk[3] = hi[1];
                *(f16x4*)(pw_base + qb * 16 * PSTRIDE + kb * 16) = pk;
            }
        }
    }

    // ---- steady state: merged { QK(t) -> buf[t&1] } / { PV+denom(t-1) } ----
    #pragma unroll 1
    for (int t = 1; t < 16; t++) {
        const int kvc = (kt0 + t) * 64;        // current tile (QK^T)
        const int kvp = kvc - 64;              // previous tile (PV)
        _Float16* pw = pw_base + (t & 1) * (64 * PSTRIDE);
        const _Float16* pr = pr_base + ((t & 1) ^ 1) * (64 * PSTRIDE);
        const _Float16* Kt = Krow + kvc * DHEAD;
        f16x8 pa[4];
        #pragma unroll
        for (int c = 0; c < 4; c++) {
            // -- QK chunk kb=c for tile t
            f16x8 k0 = *(const f16x8*)(Kt + c * 16 * DHEAD);
            f16x8 k1 = *(const f16x8*)(Kt + c * 16 * DHEAD + 32);
            #pragma unroll
            for (int qb = 0; qb < 4; qb++) {
                f32x4 a = {0.f, 0.f, 0.f, 0.f};
                a = __builtin_amdgcn_mfma_f32_16x16x32_f16(k0, qf[qb][0], a, 0, 0, 0);
                a = __builtin_amdgcn_mfma_f32_16x16x32_f16(k1, qf[qb][1], a, 0, 0, 0);
                float p0 = (a[0] > tau2) ? __builtin_amdgcn_exp2f(a[0]) : 1.0f;
                float p1 = (a[1] > tau2) ? __builtin_amdgcn_exp2f(a[1]) : 1.0f;
                float p2 = (a[2] > tau2) ? __builtin_amdgcn_exp2f(a[2]) : 1.0f;
                float p3 = (a[3] > tau2) ? __builtin_amdgcn_exp2f(a[3]) : 1.0f;
                f16x2 lo = pkrtz(p0, p1);
                f16x2 hi = pkrtz(p2, p3);
                f16x4 pk;
                pk[0] = lo[0]; pk[1] = lo[1]; pk[2] = hi[0]; pk[3] = hi[1];
                *(f16x4*)(pw + qb * 16 * PSTRIDE + c * 16) = pk;
            }
            // -- PV quarter for tile t-1: ks = c>>1, db pair = (c&1)*2
            const int ks = c >> 1, db0 = (c & 1) * 2;
            if ((c & 1) == 0) {
                #pragma unroll
                for (int qb = 0; qb < 4; qb++)
                    pa[qb] = *(const f16x8*)(pr + qb * 16 * PSTRIDE + ks * 32);
                // denominator on the idle MFMA pipe, same pa as PV (r16-verified)
                #pragma unroll
                for (int qb = 0; qb < 4; qb++)
                    accd[qb] = __builtin_amdgcn_mfma_f32_16x16x32_f16(pa[qb], ones, accd[qb], 0, 0, 0);
            }
            #pragma unroll
            for (int dd = 0; dd < 2; dd++) {
                const int db = db0 + dd;
                f16x8 vf = *(const f16x8*)(Vrow + db * 16 * SEQ + kvp + ks * 32);
                #pragma unroll
                for (int qb = 0; qb < 4; qb++)
                    O[qb][db] = __builtin_amdgcn_mfma_f32_16x16x32_f16(pa[qb], vf, O[qb][db], 0, 0, 0);
            }
        }
    }

    // ---- pipeline drain: PV + denom for tile 15 from buf[1] ----
    {
        const int kvp = (kt0 + 15) * 64;
        const _Float16* pr = pr_base + (15 & 1) * (64 * PSTRIDE);
        #pragma unroll
        for (int ks = 0; ks < 2; ks++) {
            f16x8 pa[4];
            #pragma unroll
            for (int qb = 0; qb < 4; qb++)
                pa[qb] = *(const f16x8*)(pr + qb * 16 * PSTRIDE + ks * 32);
            #pragma unroll
            for (int qb = 0; qb < 4; qb++)
                accd[qb] = __builtin_amdgcn_mfma_f32_16x16x32_f16(pa[qb], ones, accd[qb], 0, 0, 0);
            #pragma unroll
            for (int db = 0; db < 4; db++) {
                f16x8 vf = *(const f16x8*)(Vrow + db * 16 * SEQ + kvp + ks * 32);
                #pragma unroll
                for (int qb = 0; qb < 4; qb++)
                    O[qb][db] = __builtin_amdgcn_mfma_f32_16x16x32_f16(pa[qb], vf, O[qb][db], 0, 0, 0);
            }
        }
    }

    // ---- epilogue: store fp32 partials (no shuffle reduce - denom is in accd) ----
    float* Ob = Opart + (size_t)((sp * 8 + bh) * SEQ + q0) * DHEAD;
    #pragma unroll
    for (int qb = 0; qb < 4; qb++)
        #pragma unroll
        for (int db = 0; db < 4; db++)
            #pragma unroll
            for (int r = 0; r < 4; r++)
                Ob[(qb * 16 + quad * 4 + r) * DHEAD + db * 16 + l15] = O[qb][db][r];
    // accd[qb][r] = denom for q = q0+qb*16+quad*4+r, replicated over l15
    if (l15 == 0) {
        #pragma unroll
        for (int qb = 0; qb < 4; qb++)
            #pragma unroll
            for (int r = 0; r < 4; r++)
                lpart[(sp * 8 + bh) * SEQ + q0 + qb * 16 + quad * 4 + r] = accd[qb][r];
    }
}

// ---------------- Kernel 3: fused combine + output projection, single pass --------
// Single pass over all 256 output cols (ct 0..15); Opart read once (32 MB);
// f16 pre-converted weights. grid 256 row-blocks x 128 thr.
__global__ __launch_bounds__(128) void sta_oproj2(
    const float* __restrict__ Opart, const float* __restrict__ lpart,
    const _Float16* __restrict__ w16o, const float* __restrict__ ob,
    float* __restrict__ out)
{
    const int wave = threadIdx.x >> 6;
    const int lane = threadIdx.x & 63;
    const int l15  = lane & 15;
    const int quad = lane >> 4;
    const int row0 = blockIdx.x * 32 + wave * 16;

    const int nglob = row0 + l15;
    const int b = nglob >> 12, n = nglob & (SEQ - 1);

    // af[ks][j] = AO[nglob][ks*32 + quad*8 + j]  (h = ks>>1, dh = (ks&1)*32+quad*8+j)
    f16x8 af[8];
    #pragma unroll
    for (int h = 0; h < 4; h++) {
        const int bhh = b * NHEAD + h;
        float lsum = 0.f;
        #pragma unroll
        for (int s = 0; s < 4; s++) lsum += lpart[(s * 8 + bhh) * SEQ + n];
        const float inv = 1.0f / lsum;
        #pragma unroll
        for (int dp = 0; dp < 2; dp++) {
            const int dh0 = dp * 32 + quad * 8;
            float a0x=0.f,a0y=0.f,a0z=0.f,a0w=0.f,a1x=0.f,a1y=0.f,a1z=0.f,a1w=0.f;
            #pragma unroll
            for (int s = 0; s < 4; s++) {
                const float* p = Opart + (size_t)((s * 8 + bhh) * SEQ + n) * DHEAD + dh0;
                const float4 t0 = *(const float4*)p;
                const float4 t1 = *(const float4*)(p + 4);
                a0x += t0.x; a0y += t0.y; a0z += t0.z; a0w += t0.w;
                a1x += t1.x; a1y += t1.y; a1z += t1.z; a1w += t1.w;
            }
            f16x8 v;
            v[0] = (_Float16)(a0x * inv); v[1] = (_Float16)(a0y * inv);
            v[2] = (_Float16)(a0z * inv); v[3] = (_Float16)(a0w * inv);
            v[4] = (_Float16)(a1x * inv); v[5] = (_Float16)(a1y * inv);
            v[6] = (_Float16)(a1z * inv); v[7] = (_Float16)(a1w * inv);
            af[h * 2 + dp] = v;
        }
    }

    #pragma unroll 1
    for (int ct = 0; ct < 16; ct++) {
        const _Float16* wr = w16o + (ct * 16 + l15) * CDIM + quad * 8;
        f32x4 acc = {0.f, 0.f, 0.f, 0.f};
        #pragma unroll
        for (int ks = 0; ks < 8; ks++)
            acc = __builtin_amdgcn_mfma_f32_16x16x32_f16(*(const f16x8*)(wr + ks * 32), af[ks], acc, 0, 0, 0);
        const int c0 = ct * 16 + quad * 4;
        const float4 bv = *(const float4*)(ob + c0);
        float4 res;
        res.x = acc[0] + bv.x; res.y = acc[1] + bv.y;
        res.z = acc[2] + bv.z; res.w = acc[3] + bv.w;
        *(float4*)(out + (size_t)nglob * CDIM + c0) = res;
    }
}

extern "C" void kernel_launch(void* const* d_in, const int* in_sizes, int n_in,
                              void* d_out, int out_size, void* d_ws, size_t ws_size,
                              hipStream_t stream) {
    const float* x   = (const float*)d_in[0];
    const float* qw  = (const float*)d_in[1];
    const float* qb  = (const float*)d_in[2];
    const float* kw  = (const float*)d_in[3];
    const float* kb  = (const float*)d_in[4];
    const float* vw  = (const float*)d_in[5];
    const float* vb  = (const float*)d_in[6];
    const float* ow  = (const float*)d_in[7];
    const float* ob  = (const float*)d_in[8];
    const float* tau = (const float*)d_in[9];

    _Float16* w16 = (_Float16*)d_ws;
    _Float16* Q   = w16 + 262144;
    _Float16* K   = Q + 2097152;
    _Float16* Vt  = K + 2097152;
    float* Opart  = (float*)(Vt + 2097152);           // 4 sp x 8 bh x 4096 x 64 f32 = 32 MB
    float* lpart  = Opart + 8388608;                  // 4 sp x 8 bh x 4096 f32

    sta_prep  <<<dim3(32, 4),      256, 0, stream>>>(qw, kw, vw, ow, w16);
    sta_qkv   <<<dim3(128, 3, 2),  256, 0, stream>>>(x, w16, qb, kb, vb, Q, K, Vt);
    sta_attn  <<<dim3(64, 8, 4),    64, 0, stream>>>(Q, K, Vt, tau, Opart, lpart);
    sta_oproj2<<<256,              128, 0, stream>>>(Opart, lpart, w16 + 3 * 65536, ob, (float*)d_out);
}